// Round 12
// baseline (73.545 us; speedup 1.0000x reference)
//
#include <hip/hip_runtime.h>

#define NB 8
#define CHW 6300
#define TT 500
#define OUT 128
#define NO 1024
#define NK32 200          // total k32 steps (padded: 6300 -> 6400)
#define KSPLIT 8
#define NKC (NK32/KSPLIT) // 25 k32 per ks
#define CK 4              // k32 per shared-W LDS chunk

typedef __attribute__((ext_vector_type(8))) _Float16 f16x8;
typedef __attribute__((ext_vector_type(4))) float f32x4;

// lgkm-only workgroup barrier: does NOT drain vmcnt (x prefetches stay in flight)
__device__ __forceinline__ void wg_barrier_lgkm() {
    asm volatile("s_waitcnt lgkmcnt(0)" ::: "memory");
    __builtin_amdgcn_s_barrier();
}

// ---------------- Kernel 1: pack W into MFMA A-fragment order ----------------
// Wp[hl][k32][of][lane][8]; o=of*16+(lane&15), c=k32*32+(lane>>4)*8+i
// hl=0: f16(W); hl=1: f16((W - f16(W)) * 2048). Zero-padded for c>=CHW.
__global__ __launch_bounds__(512) void packW(const float* __restrict__ W,
                                             _Float16* __restrict__ Wp) {
    const int tid = threadIdx.x;
    const int of = tid >> 6;
    const int lane = tid & 63;
    const int k32 = blockIdx.x;
    const int hl = blockIdx.y;
    const int o = of * 16 + (lane & 15);
    const int cb = k32 * 32 + (lane >> 4) * 8;

    union { _Float16 h[8]; uint4 u; } tmp;
#pragma unroll
    for (int i = 0; i < 8; i++) {
        int c = cb + i;
        float w = (c < CHW) ? W[(size_t)o * CHW + c] : 0.f;
        _Float16 hi = (_Float16)w;
        tmp.h[i] = (hl == 0) ? hi : (_Float16)((w - (float)hi) * 2048.f);
    }
    size_t lr = (((size_t)hl * NK32 + k32) * 8 + of) * 64 + lane;
    *(uint4*)(Wp + lr * 8) = tmp.u;
}

// ---------------- Kernel 2: barrier-free per-wave MFMA GEMM ----------------
// Each wave independently computes a 16t x 128o x (K/8) tile:
//   x streamed via depth-4 register queue -> private in-order LDS transpose
//   (no barriers on the x path); W A-frags from block-shared LDS chunk,
//   restaged every CK k32 steps (lgkm-only barriers, 14 total).
__global__ __launch_bounds__(256, 2) void gemm(const float* __restrict__ x,
                                               const _Float16* __restrict__ Wp,
                                               float* __restrict__ vp) {
    const int L = blockIdx.x;            // 0..511
    const int ks = L & 7;                // XCD-aligned k-split (L%8 = XCD rr)
    const int TG = L >> 3;               // 0..63
    const int tid = threadIdx.x;
    const int w = tid >> 6;              // wave 0..3
    const int lane = tid & 63;
    const int l15 = lane & 15;
    const int lg = lane >> 4;            // 0..3
    const int T = TG * 4 + w;            // 0..255: per-wave tile
    const int n = T >> 5;                // 0..7
    const int t0 = (T & 31) * 16;        // 0..496
    const int k32_0 = ks * NKC;

    __shared__ __align__(16) _Float16 Wl[CK][16][512];  // 64KB shared W chunk
    __shared__ float Xl[4][32][17];                     // 8.7KB per-wave x tile

    const float* xn = x + (size_t)n * CHW * TT;
    const int xr = lane >> 2;            // x stage row 0..15 (+16p)
    const int xc4 = (lane & 3) * 4;      // t sub-chunk
    const bool t_ok = (t0 + xc4 + 4) <= TT;  // full float4 in range
    const float4 f4z = make_float4(0.f, 0.f, 0.f, 0.f);

    f32x4 acc[8][2] = {};                // [of][hl]
    float4 q0[2], q1[2], q2[2], q3[2];   // x queue, depth 4 (all static slots)

#define XG(qq, it_)                                                            \
    {                                                                          \
        _Pragma("unroll") for (int p_ = 0; p_ < 2; p_++) {                     \
            const int c_ = (k32_0 + (it_)) * 32 + xr + 16 * p_;                \
            qq[p_] = (c_ < CHW && t_ok)                                        \
                ? *(const float4*)(xn + (size_t)c_ * TT + t0 + xc4)            \
                : f4z;                                                         \
        }                                                                      \
    }

#define DSW(qq)                                                                \
    {                                                                          \
        _Pragma("unroll") for (int p_ = 0; p_ < 2; p_++) {                     \
            const int r_ = xr + 16 * p_;                                       \
            Xl[w][r_][xc4 + 0] = qq[p_].x;                                     \
            Xl[w][r_][xc4 + 1] = qq[p_].y;                                     \
            Xl[w][r_][xc4 + 2] = qq[p_].z;                                     \
            Xl[w][r_][xc4 + 3] = qq[p_].w;                                     \
        }                                                                      \
    }

#define TRANS(bfr_)                                                            \
    {                                                                          \
        union { _Float16 h[8]; f16x8 v; } tc_;                                 \
        _Pragma("unroll") for (int i_ = 0; i_ < 8; i_++)                       \
            tc_.h[i_] = (_Float16)Xl[w][lg * 8 + i_][l15];                     \
        bfr_ = tc_.v;                                                          \
    }

#define STEPCOMP(kk_, bfr_)                                                    \
    {                                                                          \
        _Pragma("unroll") for (int of_ = 0; of_ < 8; of_++)                    \
            _Pragma("unroll") for (int hl_ = 0; hl_ < 2; hl_++) {              \
                f16x8 a_ = *(const f16x8*)&Wl[kk_][of_ * 2 + hl_][lane * 8];   \
                acc[of_][hl_] = __builtin_amdgcn_mfma_f32_16x16x32_f16(        \
                    a_, bfr_, acc[of_][hl_], 0, 0, 0);                         \
            }                                                                  \
    }

// One pipeline step: consume LDS tile it=c0+kk (TRANS), write tile it+1,
// refill freed slot with tile it+4, then 16 MFMAs against shared Wl chunk.
#define STEP(kk_, qcur_, qnext_)                                               \
    {                                                                          \
        f16x8 bfr_;                                                            \
        TRANS(bfr_)                                                            \
        if (c0 + (kk_) + 1 < NKC) { DSW(qnext_) }                              \
        if (c0 + (kk_) + 4 < NKC) { XG(qcur_, c0 + (kk_) + 4) }                \
        STEPCOMP(kk_, bfr_)                                                    \
    }

    // x pipeline prologue: tiles 0..3 in registers, tile 0 -> LDS
    XG(q0, 0)
    XG(q1, 1)
    XG(q2, 2)
    XG(q3, 3)
    DSW(q0)

    for (int ck = 0; ck < 7; ++ck) {
        const int c0 = ck * CK;                        // 0,4,...,24
        const int csz = (c0 + CK <= NKC) ? CK : (NKC - c0);  // 4,...,4,1

        // restage shared W chunk (all 256 threads; lgkm-only barriers)
        wg_barrier_lgkm();
        for (int i_ = 0; i_ < csz * 4; ++i_) {
            int f_ = i_ * 4 + (tid >> 6);
            int kk_ = f_ >> 4, ofhl_ = f_ & 15;
            int of_ = ofhl_ >> 1, hl_ = ofhl_ & 1;
            int k32_ = k32_0 + c0 + kk_;
            uint4 v_ = *(const uint4*)(Wp +
                ((((size_t)hl_ * NK32 + k32_) * 8 + of_) * 64 + lane) * 8);
            *(uint4*)&Wl[kk_][ofhl_][lane * 8] = v_;
        }
        wg_barrier_lgkm();

        if (csz == CK) {
            STEP(0, q0, q1)
            STEP(1, q1, q2)
            STEP(2, q2, q3)
            STEP(3, q3, q0)
        } else {
            STEP(0, q0, q1)
        }
    }

    // epilogue: D col(l&15)=t, row=lg*4+r = o-within-frag; combine hi/lo
    const float inv = 1.f / 2048.f;
    const int t = t0 + l15;
    if (t < TT) {
#pragma unroll
        for (int of = 0; of < 8; of++) {
            f32x4 vo;
#pragma unroll
            for (int r = 0; r < 4; r++)
                vo[r] = acc[of][0][r] + acc[of][1][r] * inv;
            *(f32x4*)(vp + (((size_t)ks * TT + t) * NB + n) * OUT +
                      of * 16 + lg * 4) = vo;
        }
    }
#undef XG
#undef DSW
#undef TRANS
#undef STEPCOMP
#undef STEP
}

// ---------------- Kernel 3: wave-specialized alpha+spike scan, fused 8-partial ----
// 32 blocks x 512 thr, 32 chains/block. Wave 0 (lanes 0-31): serial G/H
// recursion; waves 1-7: stage next slab with 8-partial K-sum fused (fixed order).
#define SCN_RA 0.9048374180359595f       // exp(-0.1)
#define SCN_RACA 0.24596031111569496f    // RA*CA = 0.1*e^0.9
#define SCN_RS 0.36787944117144233f      // exp(-1)
#define SCN_RSCS -20.0f                  // RS*CS (CS = -20e)
#define SCN_RSCS2 -40.0f                 // 2*RS*CS
#define SCN_RSRSCS -7.3575888234288467f  // RS*RS*CS
#define SCN_TH 10.0f

#define CHAIN_STEP(i)                                                   \
    {                                                                   \
        float ua = Aa;                                                  \
        float w = fmaf(SCN_RS, G, ua);                                  \
        float u = sp ? (w + SCN_RSCS) : w;                              \
        bool sn = (u >= SCN_TH);                                        \
        sbuf[i][lane] = sn ? 1.f : 0.f;                                 \
        float Gb = fmaf(SCN_RS, G, H);                                  \
        G = sp ? (Gb + SCN_RSCS2) : Gb;                                 \
        float Hb = SCN_RS * H;                                          \
        H = sp ? (Hb + SCN_RSRSCS) : Hb;                                \
        sp = sn;                                                        \
        Ba = fmaf(SCN_RA, Ba, SCN_RACA * vv[i]);                        \
        Aa = fmaf(SCN_RA, Aa, Ba);                                      \
    }

__global__ __launch_bounds__(512) void scanspike(const float* __restrict__ vp,
                                                 float* __restrict__ out) {
    const int tid = threadIdx.x;
    const int wave = tid >> 6;
    const int lane = tid & 63;
    const int l5 = lane & 31;
    const int rh = lane >> 5;
    const int g0 = blockIdx.x * 32;
    const int cn = g0 >> 7;
    const int co = (g0 & 127) + l5;

    __shared__ float vbuf[2][64][32];
    __shared__ float sbuf[64][33];

    for (int rp = wave; rp * 2 < 64; rp += 8) {
        int r = rp * 2 + rh;
        float a = 0.f;
#pragma unroll
        for (int k = 0; k < KSPLIT; k++)
            a += vp[(((size_t)k * TT + r) * NB + cn) * OUT + co];
        vbuf[0][r][l5] = a;
    }
    __syncthreads();

    float Aa = 0.f, Ba = 0.f, G = 0.f, H = 0.f;
    bool sp = false;

    for (int tb = 0; tb < 8; ++tb) {
        const int cur = tb & 1;
        const int t0 = tb * 64;
        const int cnt = (tb == 7) ? 52 : 64;

        if (wave == 0) {
            if (lane < 32) {
                if (cnt == 64) {
                    float vv[64];
#pragma unroll
                    for (int i = 0; i < 64; ++i) vv[i] = vbuf[cur][i][l5];
#pragma unroll
                    for (int i = 0; i < 64; ++i) CHAIN_STEP(i)
                } else {
                    float vv[52];
#pragma unroll
                    for (int i = 0; i < 52; ++i) vv[i] = vbuf[cur][i][l5];
#pragma unroll
                    for (int i = 0; i < 52; ++i) CHAIN_STEP(i)
                }
            }
        } else if (tb < 7) {
            const int nt0 = t0 + 64;
            const int ncnt = (tb == 6) ? 52 : 64;
            for (int rp = wave - 1; rp * 2 < ncnt; rp += 7) {
                int r = rp * 2 + rh;
                float a = 0.f;
#pragma unroll
                for (int k = 0; k < KSPLIT; k++)
                    a += vp[(((size_t)k * TT + nt0 + r) * NB + cn) * OUT + co];
                vbuf[cur ^ 1][r][l5] = a;
            }
        }
        __syncthreads();

#pragma unroll
        for (int j = 0; j < 4; ++j) {
            int cc = wave * 4 + j;
            int oo = (g0 & 127) + cc;
            if (lane < cnt)
                out[((size_t)cn * OUT + oo) * TT + t0 + lane] = sbuf[lane][cc];
        }
        __syncthreads();
    }
}

extern "C" void kernel_launch(void* const* d_in, const int* in_sizes, int n_in,
                              void* d_out, int out_size, void* d_ws, size_t ws_size,
                              hipStream_t stream) {
    const float* x = (const float*)d_in[0];   // [8,2,50,63,500] fp32
    const float* W = (const float*)d_in[1];   // [128,6300] fp32
    float* out = (float*)d_out;               // [8,128,1,1,500] fp32

    _Float16* Wp = (_Float16*)d_ws;                      //  3,276,800 B
    float*    vp = (float*)((char*)d_ws + 3276800);      // 16,384,000 B

    packW<<<dim3(NK32, 2), 512, 0, stream>>>(W, Wp);
    gemm<<<512, 256, 0, stream>>>(x, Wp, vp);
    scanspike<<<32, 512, 0, stream>>>(vp, out);
}

// Round 13
// 72.629 us; speedup vs baseline: 1.0126x; 1.0126x over previous
//
#include <hip/hip_runtime.h>

#define NB 8
#define CHW 6300
#define TT 500
#define OUT 128
#define NO 1024
#define NK32 200          // total k32 steps (padded: 6300 -> 6400)
#define KSPLIT 8
#define NKC (NK32/KSPLIT) // 25 k32 per ks

typedef __attribute__((ext_vector_type(8))) _Float16 f16x8;
typedef __attribute__((ext_vector_type(4))) float f32x4;

// ---------------- Kernel 1: pack W into MFMA A-fragment order ----------------
// Wp[hl][k32][of][lane][8]; o=of*16+(lane&15), c=k32*32+(lane>>4)*8+i
// hl=0: f16(W); hl=1: f16((W - f16(W)) * 2048). Zero-padded for c>=CHW.
__global__ __launch_bounds__(512) void packW(const float* __restrict__ W,
                                             _Float16* __restrict__ Wp) {
    const int tid = threadIdx.x;
    const int of = tid >> 6;
    const int lane = tid & 63;
    const int k32 = blockIdx.x;
    const int hl = blockIdx.y;
    const int o = of * 16 + (lane & 15);
    const int cb = k32 * 32 + (lane >> 4) * 8;

    union { _Float16 h[8]; uint4 u; } tmp;
#pragma unroll
    for (int i = 0; i < 8; i++) {
        int c = cb + i;
        float w = (c < CHW) ? W[(size_t)o * CHW + c] : 0.f;
        _Float16 hi = (_Float16)w;
        tmp.h[i] = (hl == 0) ? hi : (_Float16)((w - (float)hi) * 2048.f);
    }
    size_t lr = (((size_t)hl * NK32 + k32) * 8 + of) * 64 + lane;
    *(uint4*)(Wp + lr * 8) = tmp.u;
}

// ---------------- Kernel 2: fully-decoupled per-wave MFMA GEMM ----------------
// ZERO barriers, ZERO shared LDS. Each wave: independent 16t x 128o x (K/8) tile.
//  - W frags: register double-buffer (wA/wB), 8 independent dwordx4 L2 loads per
//    step, prefetched one step ahead (L2 latency hidden under 16 MFMAs).
//  - x: depth-2 register queue -> private per-wave LDS tile (in-order ds ops).
//  - 16 independent MFMA accumulators per step.
__global__ __launch_bounds__(256, 2) void gemm(const float* __restrict__ x,
                                               const _Float16* __restrict__ Wp,
                                               float* __restrict__ vp) {
    const int L = blockIdx.x;            // 0..511
    const int ks = L & 7;                // XCD-affine k-split
    const int n  = (L >> 3) & 7;
    const int tg = L >> 6;               // 0..7
    const int tid = threadIdx.x;
    const int w = tid >> 6;              // wave 0..3
    const int lane = tid & 63;
    const int l15 = lane & 15;
    const int lg = lane >> 4;            // 0..3
    const int t0 = (tg * 4 + w) * 16;    // 0..496
    const int k32_0 = ks * NKC;

    __shared__ float Xl[4][32][17];      // per-wave private x tile (8.7KB)

    const float* xn = x + (size_t)n * CHW * TT;
    const int xr = lane >> 2;            // 0..15 (c-row within half)
    const int xc4 = (lane & 3) * 4;      // t sub-chunk
    const bool t_ok = (t0 + xc4 + 4) <= TT;
    const float4 f4z = make_float4(0.f, 0.f, 0.f, 0.f);

    f32x4 acc[8][2] = {};                // [of][hl]: 16t x 128o
    f16x8 wA[16], wB[16];                // W frag dbuf [of*2+hl]
    float4 q0[2], q1[2];                 // x queue depth 2 (static)

#define XG(qq, it_)                                                            \
    {                                                                          \
        _Pragma("unroll") for (int p_ = 0; p_ < 2; p_++) {                     \
            const int c_ = (k32_0 + (it_)) * 32 + xr + 16 * p_;                \
            qq[p_] = (c_ < CHW && t_ok)                                        \
                ? *(const float4*)(xn + (size_t)c_ * TT + t0 + xc4)            \
                : f4z;                                                         \
        }                                                                      \
    }

#define DSW(qq)                                                                \
    {                                                                          \
        _Pragma("unroll") for (int p_ = 0; p_ < 2; p_++) {                     \
            const int r_ = xr + 16 * p_;                                       \
            Xl[w][r_][xc4 + 0] = qq[p_].x;                                     \
            Xl[w][r_][xc4 + 1] = qq[p_].y;                                     \
            Xl[w][r_][xc4 + 2] = qq[p_].z;                                     \
            Xl[w][r_][xc4 + 3] = qq[p_].w;                                     \
        }                                                                      \
    }

#define TRANS(bfr_)                                                            \
    {                                                                          \
        union { _Float16 h[8]; f16x8 v; } tc_;                                 \
        _Pragma("unroll") for (int i_ = 0; i_ < 8; i_++)                       \
            tc_.h[i_] = (_Float16)Xl[w][lg * 8 + i_][l15];                     \
        bfr_ = tc_.v;                                                          \
    }

#define WRL(wd, it_)                                                           \
    _Pragma("unroll") for (int f_ = 0; f_ < 16; f_++) {                        \
        const int hl_ = f_ & 1, of_ = f_ >> 1;                                 \
        wd[f_] = *(const f16x8*)(Wp +                                          \
            ((((size_t)hl_ * NK32 + k32_0 + (it_)) * 8 + of_) * 64 + lane) * 8); \
    }

#define COMP(bfr_, wd)                                                         \
    _Pragma("unroll") for (int of_ = 0; of_ < 8; of_++)                        \
        _Pragma("unroll") for (int hl_ = 0; hl_ < 2; hl_++)                    \
            acc[of_][hl_] = __builtin_amdgcn_mfma_f32_16x16x32_f16(            \
                wd[of_ * 2 + hl_], bfr_, acc[of_][hl_], 0, 0, 0);

    // prologue: W frags for step 0; x tiles 0,1 in regs; tile 0 -> LDS
    WRL(wA, 0)
    XG(q0, 0)
    XG(q1, 1)
    DSW(q0)

    for (int p = 0; p < 12; ++p) {
        // even step s=2p: compute tile s with wA; prefetch W(s+1), x(s+2)
        {
            const int s = 2 * p;
            WRL(wB, s + 1)
            XG(q0, s + 2)                // s+2 <= 24 always
            f16x8 bfr;
            TRANS(bfr)                   // tile s
            DSW(q1)                      // tile s+1
            COMP(bfr, wA)
        }
        // odd step s=2p+1
        {
            const int s = 2 * p + 1;
            WRL(wA, s + 1)               // s+1 <= 24 always
            if (p < 11) { XG(q1, s + 2) }
            f16x8 bfr;
            TRANS(bfr)                   // tile s
            DSW(q0)                      // tile s+1
            COMP(bfr, wB)
        }
    }
    // tail s = 24 (wA, tile 24 already in Xl)
    {
        f16x8 bfr;
        TRANS(bfr)
        COMP(bfr, wA)
    }

    // epilogue: D col(l&15)=t, row=lg*4+r = o-within-frag; combine hi/lo
    const float inv = 1.f / 2048.f;
    const int t = t0 + l15;
    if (t < TT) {
#pragma unroll
        for (int of = 0; of < 8; of++) {
            f32x4 vo;
#pragma unroll
            for (int r = 0; r < 4; r++)
                vo[r] = acc[of][0][r] + acc[of][1][r] * inv;
            *(f32x4*)(vp + (((size_t)ks * TT + t) * NB + n) * OUT +
                      of * 16 + lg * 4) = vo;
        }
    }
#undef XG
#undef DSW
#undef TRANS
#undef WRL
#undef COMP
}

// ---------------- Kernel 3: wave-specialized alpha+spike scan, fused 8-partial ----
// 32 blocks x 512 thr, 32 chains/block. Wave 0 (lanes 0-31): serial G/H
// recursion; waves 1-7: stage next slab with 8-partial K-sum fused (fixed order).
#define SCN_RA 0.9048374180359595f       // exp(-0.1)
#define SCN_RACA 0.24596031111569496f    // RA*CA = 0.1*e^0.9
#define SCN_RS 0.36787944117144233f      // exp(-1)
#define SCN_RSCS -20.0f                  // RS*CS (CS = -20e)
#define SCN_RSCS2 -40.0f                 // 2*RS*CS
#define SCN_RSRSCS -7.3575888234288467f  // RS*RS*CS
#define SCN_TH 10.0f

#define CHAIN_STEP(i)                                                   \
    {                                                                   \
        float ua = Aa;                                                  \
        float w = fmaf(SCN_RS, G, ua);                                  \
        float u = sp ? (w + SCN_RSCS) : w;                              \
        bool sn = (u >= SCN_TH);                                        \
        sbuf[i][lane] = sn ? 1.f : 0.f;                                 \
        float Gb = fmaf(SCN_RS, G, H);                                  \
        G = sp ? (Gb + SCN_RSCS2) : Gb;                                 \
        float Hb = SCN_RS * H;                                          \
        H = sp ? (Hb + SCN_RSRSCS) : Hb;                                \
        sp = sn;                                                        \
        Ba = fmaf(SCN_RA, Ba, SCN_RACA * vv[i]);                        \
        Aa = fmaf(SCN_RA, Aa, Ba);                                      \
    }

__global__ __launch_bounds__(512) void scanspike(const float* __restrict__ vp,
                                                 float* __restrict__ out) {
    const int tid = threadIdx.x;
    const int wave = tid >> 6;
    const int lane = tid & 63;
    const int l5 = lane & 31;
    const int rh = lane >> 5;
    const int g0 = blockIdx.x * 32;
    const int cn = g0 >> 7;
    const int co = (g0 & 127) + l5;

    __shared__ float vbuf[2][64][32];
    __shared__ float sbuf[64][33];

    for (int rp = wave; rp * 2 < 64; rp += 8) {
        int r = rp * 2 + rh;
        float a = 0.f;
#pragma unroll
        for (int k = 0; k < KSPLIT; k++)
            a += vp[(((size_t)k * TT + r) * NB + cn) * OUT + co];
        vbuf[0][r][l5] = a;
    }
    __syncthreads();

    float Aa = 0.f, Ba = 0.f, G = 0.f, H = 0.f;
    bool sp = false;

    for (int tb = 0; tb < 8; ++tb) {
        const int cur = tb & 1;
        const int t0 = tb * 64;
        const int cnt = (tb == 7) ? 52 : 64;

        if (wave == 0) {
            if (lane < 32) {
                if (cnt == 64) {
                    float vv[64];
#pragma unroll
                    for (int i = 0; i < 64; ++i) vv[i] = vbuf[cur][i][l5];
#pragma unroll
                    for (int i = 0; i < 64; ++i) CHAIN_STEP(i)
                } else {
                    float vv[52];
#pragma unroll
                    for (int i = 0; i < 52; ++i) vv[i] = vbuf[cur][i][l5];
#pragma unroll
                    for (int i = 0; i < 52; ++i) CHAIN_STEP(i)
                }
            }
        } else if (tb < 7) {
            const int nt0 = t0 + 64;
            const int ncnt = (tb == 6) ? 52 : 64;
            for (int rp = wave - 1; rp * 2 < ncnt; rp += 7) {
                int r = rp * 2 + rh;
                float a = 0.f;
#pragma unroll
                for (int k = 0; k < KSPLIT; k++)
                    a += vp[(((size_t)k * TT + nt0 + r) * NB + cn) * OUT + co];
                vbuf[cur ^ 1][r][l5] = a;
            }
        }
        __syncthreads();

#pragma unroll
        for (int j = 0; j < 4; ++j) {
            int cc = wave * 4 + j;
            int oo = (g0 & 127) + cc;
            if (lane < cnt)
                out[((size_t)cn * OUT + oo) * TT + t0 + lane] = sbuf[lane][cc];
        }
        __syncthreads();
    }
}

extern "C" void kernel_launch(void* const* d_in, const int* in_sizes, int n_in,
                              void* d_out, int out_size, void* d_ws, size_t ws_size,
                              hipStream_t stream) {
    const float* x = (const float*)d_in[0];   // [8,2,50,63,500] fp32
    const float* W = (const float*)d_in[1];   // [128,6300] fp32
    float* out = (float*)d_out;               // [8,128,1,1,500] fp32

    _Float16* Wp = (_Float16*)d_ws;                      //  3,276,800 B
    float*    vp = (float*)((char*)d_ws + 3276800);      // 16,384,000 B

    packW<<<dim3(NK32, 2), 512, 0, stream>>>(W, Wp);
    gemm<<<512, 256, 0, stream>>>(x, Wp, vp);
    scanspike<<<32, 512, 0, stream>>>(vp, out);
}